// Round 8
// baseline (151.708 us; speedup 1.0000x reference)
//
#include <hip/hip_runtime.h>
#include <math.h>

#define N_ROWS 4096
#define DIM    128
#define A_LAB  512
#define INV_TAU 14.285714285714286f
#define C_EXP   20.609929155556620f   // INV_TAU * log2(e)

typedef __attribute__((ext_vector_type(8))) short short8;   // 8 bf16 (4 VGPRs)
typedef __attribute__((ext_vector_type(4))) float f32x4;    // MFMA C/D frag (16x16)
typedef __attribute__((ext_vector_type(4))) int i32x4;      // i8 MFMA A/B frag
typedef __attribute__((ext_vector_type(16))) int i32x16;    // i8 MFMA C/D frag (32x32)

// ---------------- workspace layout (bytes) ----------------
// zbf   u16 [8192*128]   @ 0          (2,097,152)  NATURAL row-major
// labs8 i8  [4096*512]   @ 2,097,152  (2,097,152)  NATURAL row-major
// s     i32 [4096]       @ 4,194,304  (16,384)
// part  f32 [3*4096]     @ 4,210,688  (49,152)     atomically accumulated

__device__ __forceinline__ unsigned short f2bf(float f) {
  unsigned int u = __builtin_bit_cast(unsigned int, f);
  u += 0x7fffu + ((u >> 16) & 1u);            // round-to-nearest-even
  return (unsigned short)(u >> 16);
}

// ------------ kernel 1: L2-normalize (-> bf16) + labels -> i8 + row-popcount ------------
__global__ __launch_bounds__(256) void k_norm_pack(
    const float* __restrict__ z1, const float* __restrict__ z2,
    const int* __restrict__ labels,
    unsigned int* __restrict__ zbf, uint2* __restrict__ labs8,
    int* __restrict__ s, float* __restrict__ part, float* __restrict__ out)
{
  {
    const int idx = blockIdx.x * 256 + threadIdx.x;
    if (idx < 3 * 4096) part[idx] = 0.0f;
    if (idx == 0) out[0] = 0.0f;
  }
  const int wave = threadIdx.x >> 6, lane = threadIdx.x & 63;
  const int r = blockIdx.x * 4 + wave;         // 0..8191
  const float* src = (r < N_ROWS) ? (z1 + (size_t)r * DIM)
                                  : (z2 + (size_t)(r - N_ROWS) * DIM);
  float2 x = ((const float2*)src)[lane];
  float ss = x.x * x.x + x.y * x.y;
  #pragma unroll
  for (int off = 32; off > 0; off >>= 1) ss += __shfl_xor(ss, off);
  const float inv = 1.0f / fmaxf(sqrtf(ss), 1e-12f);
  const unsigned int lo = f2bf(x.x * inv);
  const unsigned int hi = f2bf(x.y * inv);
  zbf[(size_t)r * 64 + lane] = (hi << 16) | lo;           // natural layout

  if (r < N_ROWS) {
    const int4* lp = (const int4*)(labels + (size_t)r * A_LAB);
    const int4 a = lp[2 * lane], b = lp[2 * lane + 1];
    const unsigned int w0 = (unsigned int)(a.x != 0)       | ((unsigned int)(a.y != 0) << 8)
                          | ((unsigned int)(a.z != 0) << 16) | ((unsigned int)(a.w != 0) << 24);
    const unsigned int w1 = (unsigned int)(b.x != 0)       | ((unsigned int)(b.y != 0) << 8)
                          | ((unsigned int)(b.z != 0) << 16) | ((unsigned int)(b.w != 0) << 24);
    uint2 v; v.x = w0; v.y = w1;
    labs8[(size_t)r * 64 + lane] = v;                     // natural layout
    int cnt = __popc(w0) + __popc(w1);         // bytes are 0/1 -> popc == byte sum
    #pragma unroll
    for (int off = 32; off > 0; off >>= 1) cnt += __shfl_xor(cnt, off);
    if (lane == 0) s[r] = cnt;
  }
}

// ------------ kernel 2: FUSED jaccard + sim + masked-softmax, barrier-minimal ------------
// Block (bi,bj): anchors [128bi..+128) x cols {[128bj..+128), [4096+128bj..+128)}.
// NO LDS staging: all MFMA fragments (i8 jac + bf16 sim) are 16 B/lane loads
// DIRECTLY from global (L2/L3-resident); compiler pipelines them with
// fine-grained vmcnt. Only LDS use is the 2 KB pos-bit mask pmL; exactly ONE
// __syncthreads (pmL producer -> consumer), placed after all sim MFMAs issue.
// jac: 2x2 wave grid, mfma_i32_32x32x32_i8; exact threshold 13*I >= 3*(si+sj).
// sim: each wave 32 rows x 128 cols x both halves, mfma_f32_16x16x32_bf16.
// Off-diag (992/1024 blocks): slim epilogue; P from pmL popcount (not in loop).
__global__ __launch_bounds__(256, 2) void k_fused(
    const unsigned char* __restrict__ labs8, const int* __restrict__ s,
    const unsigned short* __restrict__ zbf, float* __restrict__ part)
{
  __shared__ unsigned int pmL[128 * 4];       // pos-bits: [local row][col word]
  const int tid = threadIdx.x;
  const int ibase = blockIdx.x * 128, jbase = blockIdx.y * 128;
  const int wave = tid >> 6, lane = tid & 63;
  const bool diag = (ibase == jbase);
  const char* gl = (const char*)labs8;
  const char* gz = (const char*)zbf;

  // ---------------- phase J: jaccard (global-direct fragments) ----------------
  const int jwr = (wave >> 1) * 64, jwc = (wave & 1) * 64;   // 2x2 wave grid
  const int col32 = lane & 31, h = lane >> 5;

  const int s3i = 3 * s[ibase + jwr + lane];  // epilogue s-cache (via __shfl)
  const int s3j = 3 * s[jbase + jwc + lane];

  i32x16 jacc[2][2];
  #pragma unroll
  for (int rt = 0; rt < 2; ++rt)
    #pragma unroll
    for (int nt = 0; nt < 2; ++nt)
      #pragma unroll
      for (int e = 0; e < 16; ++e) jacc[rt][nt][e] = 0;

  const int ra0 = ibase + jwr + col32;        // A rows for this lane
  const int rb0 = jbase + jwc + col32;        // B rows for this lane
  #pragma unroll
  for (int ck = 0; ck < 4; ++ck) {
    #pragma unroll
    for (int ks = 0; ks < 4; ++ks) {
      const int off = ck * 128 + ks * 32 + h * 16;   // k-byte offset in row
      i32x4 a[2], b[2];
      #pragma unroll
      for (int rt = 0; rt < 2; ++rt)
        a[rt] = *(const i32x4*)(gl + (size_t)(ra0 + rt * 32) * 512 + off);
      #pragma unroll
      for (int nt = 0; nt < 2; ++nt)
        b[nt] = *(const i32x4*)(gl + (size_t)(rb0 + nt * 32) * 512 + off);
      #pragma unroll
      for (int rt = 0; rt < 2; ++rt)
        #pragma unroll
        for (int nt = 0; nt < 2; ++nt)
          jacc[rt][nt] = __builtin_amdgcn_mfma_i32_32x32x32_i8(a[rt], b[nt], jacc[rt][nt], 0, 0, 0);
    }
  }

  // jac epilogue: threshold + ballot -> pmL
  #pragma unroll
  for (int rt = 0; rt < 2; ++rt)
    #pragma unroll
    for (int nt = 0; nt < 2; ++nt) {
      const int wl = (jwc >> 5) + nt;
      const int sj = __shfl(s3j, nt * 32 + col32);
      #pragma unroll
      for (int reg = 0; reg < 16; ++reg) {
        const int r0 = (reg & 3) + 8 * (reg >> 2);
        const int si = __shfl(s3i, rt * 32 + r0 + 4 * h);
        const bool pred = 13 * jacc[rt][nt][reg] >= si + sj;
        const unsigned long long bal = __ballot(pred);
        const int lr = jwr + rt * 32 + r0;
        if (lane == 0)      pmL[lr * 4 + wl]       = (unsigned int)bal;
        else if (lane == 1) pmL[(lr + 4) * 4 + wl] = (unsigned int)(bal >> 32);
      }
    }

  // ---------------- phase S: sim MFMAs (global-direct), then one barrier ----------------
  const int col = lane & 15, quad = lane >> 4;
  const int swr = wave * 32;                     // this wave: rows [swr, swr+32)

  short8 afr[2][4];
  #pragma unroll
  for (int rt = 0; rt < 2; ++rt)
    #pragma unroll
    for (int kf = 0; kf < 4; ++kf) {
      const int ra = ibase + swr + rt * 16 + col;
      afr[rt][kf] = *(const short8*)(gz + (size_t)ra * 256 + kf * 64 + quad * 16);
    }

  f32x4 acc[2][2][8];   // [half][rt][nt]
  #pragma unroll
  for (int half = 0; half < 2; ++half)
    #pragma unroll
    for (int rt = 0; rt < 2; ++rt)
      #pragma unroll
      for (int nt = 0; nt < 8; ++nt) acc[half][rt][nt] = (f32x4){0, 0, 0, 0};

  #pragma unroll
  for (int half = 0; half < 2; ++half) {
    const int cb = (half ? N_ROWS : 0) + jbase;
    #pragma unroll
    for (int nt = 0; nt < 8; ++nt) {
      short8 bfr[4];
      #pragma unroll
      for (int kf = 0; kf < 4; ++kf) {
        const int rb = cb + nt * 16 + col;
        bfr[kf] = *(const short8*)(gz + (size_t)rb * 256 + kf * 64 + quad * 16);
      }
      #pragma unroll
      for (int rt = 0; rt < 2; ++rt)
        #pragma unroll
        for (int kf = 0; kf < 4; ++kf)
          acc[half][rt][nt] = __builtin_amdgcn_mfma_f32_16x16x32_bf16(
              afr[rt][kf], bfr[kf], acc[half][rt][nt], 0, 0, 0);
    }
  }

  __syncthreads();   // the ONLY barrier: pmL visible to all waves

  // ---------------- epilogue: masked softmax partials ----------------
  float lacc[2][4], Sacc[2][4], Pcnt[2][4];
  #pragma unroll
  for (int rt = 0; rt < 2; ++rt)
    #pragma unroll
    for (int reg = 0; reg < 4; ++reg) { lacc[rt][reg] = 0; Sacc[rt][reg] = 0; Pcnt[rt][reg] = 0; }

  if (!diag) {
    // slim path: mask identical for both halves; no self/aug; P via popcount later
    #pragma unroll
    for (int rt = 0; rt < 2; ++rt) {
      uint4 pw[4];
      #pragma unroll
      for (int reg = 0; reg < 4; ++reg)
        pw[reg] = *(const uint4*)&pmL[(swr + rt * 16 + quad * 4 + reg) * 4];
      #pragma unroll
      for (int nt = 0; nt < 8; ++nt) {
        const int bitpos = (nt & 1) * 16 + col;
        #pragma unroll
        for (int reg = 0; reg < 4; ++reg) {
          const unsigned int w = ((const unsigned int*)&pw[reg])[nt >> 1];
          const float d0 = acc[0][rt][nt][reg];
          const float d1 = acc[1][rt][nt][reg];
          lacc[rt][reg] += exp2f(fmaf(d0, C_EXP, -C_EXP))
                         + exp2f(fmaf(d1, C_EXP, -C_EXP));
          if ((w >> bitpos) & 1) Sacc[rt][reg] += d0 + d1;
        }
      }
    }
  } else {
    #pragma unroll
    for (int half = 0; half < 2; ++half) {
      const bool left = (half == 0);
      #pragma unroll
      for (int rt = 0; rt < 2; ++rt) {
        uint4 pw[4];
        #pragma unroll
        for (int reg = 0; reg < 4; ++reg)
          pw[reg] = *(const uint4*)&pmL[(swr + rt * 16 + quad * 4 + reg) * 4];
        #pragma unroll
        for (int nt = 0; nt < 8; ++nt) {
          const int joff = nt * 16 + col;
          const int jc = jbase + joff;
          const int bitpos = joff & 31;
          #pragma unroll
          for (int reg = 0; reg < 4; ++reg) {
            const int i = ibase + swr + rt * 16 + quad * 4 + reg;
            const unsigned int w = ((const unsigned int*)&pw[reg])[nt >> 1];
            const float d = acc[half][rt][nt][reg];
            const bool bit = (w >> bitpos) & 1;
            const bool self = left && (jc == i);
            const bool pos = left ? (bit && !self) : (bit || (jc == i));
            const float e = exp2f(fmaf(d, C_EXP, -C_EXP));
            if (!self) lacc[rt][reg] += e;
            if (pos) { Sacc[rt][reg] += d; Pcnt[rt][reg] += 1.0f; }
          }
        }
      }
    }
  }

  // ---- reduce across the 16 col-lanes, atomically accumulate per-anchor ----
  #pragma unroll
  for (int rt = 0; rt < 2; ++rt)
    #pragma unroll
    for (int reg = 0; reg < 4; ++reg) {
      float l = lacc[rt][reg], S = Sacc[rt][reg], P = Pcnt[rt][reg];
      #pragma unroll
      for (int m = 1; m < 16; m <<= 1) {
        l += __shfl_xor(l, m);
        S += __shfl_xor(S, m);
        if (diag) P += __shfl_xor(P, m);
      }
      if (col == 0) {
        const int li = swr + rt * 16 + quad * 4 + reg;
        const int i = ibase + li;
        if (!diag) {
          const uint4 pw = *(const uint4*)&pmL[li * 4];
          P = 2.0f * (float)(__popc(pw.x) + __popc(pw.y) + __popc(pw.z) + __popc(pw.w));
        }
        atomicAdd(&part[i], l);
        atomicAdd(&part[4096 + i], S);
        atomicAdd(&part[8192 + i], P);
      }
    }
}

// ---------------- kernel 3: per-anchor loss + atomic final reduce ----------------
__global__ __launch_bounds__(128) void k_loss(
    const float* __restrict__ part, float* __restrict__ out)
{
  const int a = blockIdx.x * 128 + threadIdx.x;   // 0..4095
  const float l = part[a];
  const float S = part[4096 + a];
  const float P = part[8192 + a];
  const float np = fmaxf(P, 1.0f);
  float v = INV_TAU + logf(l + 1e-8f) - (S * INV_TAU) / np;
  #pragma unroll
  for (int off = 32; off > 0; off >>= 1) v += __shfl_xor(v, off);
  __shared__ float ws2[2];
  const int wave = threadIdx.x >> 6, lane = threadIdx.x & 63;
  if (lane == 0) ws2[wave] = v;
  __syncthreads();
  if (threadIdx.x == 0) atomicAdd(out, (ws2[0] + ws2[1]) * (1.0f / (float)N_ROWS));
}

extern "C" void kernel_launch(void* const* d_in, const int* in_sizes, int n_in,
                              void* d_out, int out_size, void* d_ws, size_t ws_size,
                              hipStream_t stream) {
  const float* z1 = (const float*)d_in[0];
  const float* z2 = (const float*)d_in[1];
  const int* labels = (const int*)d_in[2];
  float* out = (float*)d_out;
  char* ws = (char*)d_ws;

  unsigned int* zbf    = (unsigned int*)(ws);
  uint2* labs8         = (uint2*)(ws + 2097152);
  int* s               = (int*)(ws + 4194304);
  float* part          = (float*)(ws + 4210688);

  hipLaunchKernelGGL(k_norm_pack, dim3(2048), dim3(256), 0, stream,
                     z1, z2, labels, zbf, labs8, s, part, out);
  hipLaunchKernelGGL(k_fused, dim3(32, 32), dim3(256), 0, stream,
                     (const unsigned char*)labs8, s, (const unsigned short*)zbf, part);
  hipLaunchKernelGGL(k_loss, dim3(32), dim3(128), 0, stream, part, out);
}

// Round 9
// 114.050 us; speedup vs baseline: 1.3302x; 1.3302x over previous
//
#include <hip/hip_runtime.h>
#include <math.h>

#define N_ROWS 4096
#define DIM    128
#define A_LAB  512
#define INV_TAU 14.285714285714286f
#define C_EXP   20.609929155556620f   // INV_TAU * log2(e)

typedef __attribute__((ext_vector_type(8))) short short8;   // 8 bf16 (4 VGPRs)
typedef __attribute__((ext_vector_type(4))) float f32x4;    // MFMA C/D frag (16x16)
typedef __attribute__((ext_vector_type(4))) int i32x4;      // i8 MFMA A/B frag
typedef __attribute__((ext_vector_type(16))) int i32x16;    // i8 MFMA C/D frag (32x32)

// ---------------- workspace layout (bytes) ----------------
// zbf   u16 [8192*128]   @ 0          (2,097,152)  FRAG-MAJOR (see k_norm_pack)
// labs8 i8  [4096*512]   @ 2,097,152  (2,097,152)  FRAG-MAJOR (see k_norm_pack)
// s     i32 [4096]       @ 4,194,304  (16,384)
// part  f32 [3*4096]     @ 4,210,688  (49,152)     atomically accumulated
//
// zbf frag-major: block (g,kf), g=row>>4 (0..511), kf=0..3; block = 64 lanes x 16B
//   lane l holds row g*16+(l&15), 16B-unit kf*4+(l>>4)  -> one coalesced dwordx4
//   per bf16 16x16x32 A/B fragment.
// labs frag-major: block (g,ks), g=row>>5 (0..127), ks=0..15; block = 64 x 16B
//   lane l holds row g*32+(l&31), k-bytes ks*32+(l>>5)*16 .. +16 -> one coalesced
//   dwordx4 per i8 32x32x32 A/B fragment.

__device__ __forceinline__ unsigned short f2bf(float f) {
  unsigned int u = __builtin_bit_cast(unsigned int, f);
  u += 0x7fffu + ((u >> 16) & 1u);            // round-to-nearest-even
  return (unsigned short)(u >> 16);
}

// ------------ kernel 1: L2-normalize (-> bf16, frag-major) + labels -> i8 frag-major ------------
__global__ __launch_bounds__(256) void k_norm_pack(
    const float* __restrict__ z1, const float* __restrict__ z2,
    const int* __restrict__ labels,
    unsigned int* __restrict__ zbf, uint2* __restrict__ labs8,
    int* __restrict__ s, float* __restrict__ part, float* __restrict__ out)
{
  {
    const int idx = blockIdx.x * 256 + threadIdx.x;
    if (idx < 3 * 4096) part[idx] = 0.0f;
    if (idx == 0) out[0] = 0.0f;
  }
  const int wave = threadIdx.x >> 6, lane = threadIdx.x & 63;
  const int r = blockIdx.x * 4 + wave;         // 0..8191
  const float* src = (r < N_ROWS) ? (z1 + (size_t)r * DIM)
                                  : (z2 + (size_t)(r - N_ROWS) * DIM);
  float2 x = ((const float2*)src)[lane];
  float ss = x.x * x.x + x.y * x.y;
  #pragma unroll
  for (int off = 32; off > 0; off >>= 1) ss += __shfl_xor(ss, off);
  const float inv = 1.0f / fmaxf(sqrtf(ss), 1e-12f);
  const unsigned int lo = f2bf(x.x * inv);
  const unsigned int hi = f2bf(x.y * inv);
  {
    // row r, dword index 'lane' (bytes lane*4). unit u=lane>>2, dword p=lane&3.
    const int u = lane >> 2, p = lane & 3;
    const int kf = u >> 2, quad = u & 3;
    const int g = r >> 4;
    zbf[(size_t)(((g * 4 + kf) * 64) + ((r & 15) + (quad << 4))) * 4 + p] = (hi << 16) | lo;
  }

  if (r < N_ROWS) {
    const int4* lp = (const int4*)(labels + (size_t)r * A_LAB);
    const int4 a = lp[2 * lane], b = lp[2 * lane + 1];
    const unsigned int w0 = (unsigned int)(a.x != 0)       | ((unsigned int)(a.y != 0) << 8)
                          | ((unsigned int)(a.z != 0) << 16) | ((unsigned int)(a.w != 0) << 24);
    const unsigned int w1 = (unsigned int)(b.x != 0)       | ((unsigned int)(b.y != 0) << 8)
                          | ((unsigned int)(b.z != 0) << 16) | ((unsigned int)(b.w != 0) << 24);
    uint2 v; v.x = w0; v.y = w1;
    // row r, bytes lane*8..+8: unit ul=lane>>1, half hp=lane&1; ks=ul>>1, h=ul&1
    const int ul = lane >> 1, hp = lane & 1;
    const int ks = ul >> 1, h = ul & 1;
    const int g = r >> 5;
    labs8[(size_t)(((g * 16 + ks) * 64) + ((r & 31) + (h << 5))) * 2 + hp] = v;
    int cnt = __popc(w0) + __popc(w1);         // bytes are 0/1 -> popc == byte sum
    #pragma unroll
    for (int off = 32; off > 0; off >>= 1) cnt += __shfl_xor(cnt, off);
    if (lane == 0) s[r] = cnt;
  }
}

// ------------ kernel 2: FUSED jaccard + sim + masked-softmax, one barrier ------------
// Block (bi,bj): anchors [128bi..+128) x cols {[128bj..+128), [4096+128bj..+128)}.
// All MFMA fragments load DIRECTLY from global in frag-major layout: each frag
// is ONE coalesced 1KB dwordx4 per wave (L2/L3-resident). No LDS staging, no
// DMA drains; only LDS is the 2KB pos-mask pmL with a single __syncthreads.
__global__ __launch_bounds__(256, 2) void k_fused(
    const unsigned char* __restrict__ labs8, const int* __restrict__ s,
    const unsigned short* __restrict__ zbf, float* __restrict__ part)
{
  __shared__ unsigned int pmL[128 * 4];       // pos-bits: [local row][col word]
  const int tid = threadIdx.x;
  const int ibase = blockIdx.x * 128, jbase = blockIdx.y * 128;
  const int wave = tid >> 6, lane = tid & 63;
  const bool diag = (ibase == jbase);
  const char* gl = (const char*)labs8;
  const char* gz = (const char*)zbf;

  // ---------------- phase J: jaccard (frag-major direct loads) ----------------
  const int jwr = (wave >> 1) * 64, jwc = (wave & 1) * 64;   // 2x2 wave grid
  const int col32 = lane & 31, h = lane >> 5;

  const int s3i = 3 * s[ibase + jwr + lane];  // epilogue s-cache (via __shfl)
  const int s3j = 3 * s[jbase + jwc + lane];

  i32x16 jacc[2][2];
  #pragma unroll
  for (int rt = 0; rt < 2; ++rt)
    #pragma unroll
    for (int nt = 0; nt < 2; ++nt)
      #pragma unroll
      for (int e = 0; e < 16; ++e) jacc[rt][nt][e] = 0;

  const int gI = (ibase + jwr) >> 5;          // row-group (32 rows) indices
  const int gJ = (jbase + jwc) >> 5;
  #pragma unroll
  for (int ks = 0; ks < 16; ++ks) {
    i32x4 a[2], b[2];
    #pragma unroll
    for (int rt = 0; rt < 2; ++rt)
      a[rt] = *(const i32x4*)(gl + (size_t)(((gI + rt) * 16 + ks) * 64 + lane) * 16);
    #pragma unroll
    for (int nt = 0; nt < 2; ++nt)
      b[nt] = *(const i32x4*)(gl + (size_t)(((gJ + nt) * 16 + ks) * 64 + lane) * 16);
    #pragma unroll
    for (int rt = 0; rt < 2; ++rt)
      #pragma unroll
      for (int nt = 0; nt < 2; ++nt)
        jacc[rt][nt] = __builtin_amdgcn_mfma_i32_32x32x32_i8(a[rt], b[nt], jacc[rt][nt], 0, 0, 0);
  }

  // jac epilogue: threshold + ballot -> pmL
  #pragma unroll
  for (int rt = 0; rt < 2; ++rt)
    #pragma unroll
    for (int nt = 0; nt < 2; ++nt) {
      const int wl = (jwc >> 5) + nt;
      const int sj = __shfl(s3j, nt * 32 + col32);
      #pragma unroll
      for (int reg = 0; reg < 16; ++reg) {
        const int r0 = (reg & 3) + 8 * (reg >> 2);
        const int si = __shfl(s3i, rt * 32 + r0 + 4 * h);
        const bool pred = 13 * jacc[rt][nt][reg] >= si + sj;
        const unsigned long long bal = __ballot(pred);
        const int lr = jwr + rt * 32 + r0;
        if (lane == 0)      pmL[lr * 4 + wl]       = (unsigned int)bal;
        else if (lane == 1) pmL[(lr + 4) * 4 + wl] = (unsigned int)(bal >> 32);
      }
    }

  // sim A-fragments (issued before the barrier; independent of pmL)
  const int col = lane & 15, quad = lane >> 4;
  const int swr = wave * 32;                     // this wave: rows [swr, swr+32)
  const int gA = (ibase + swr) >> 4;             // 16-row group index
  short8 afr[2][4];
  #pragma unroll
  for (int rt = 0; rt < 2; ++rt)
    #pragma unroll
    for (int kf = 0; kf < 4; ++kf)
      afr[rt][kf] = *(const short8*)(gz + (size_t)(((gA + rt) * 4 + kf) * 64 + lane) * 16);

  __syncthreads();   // the ONLY barrier: pmL visible to all waves

  // mask words for this wave's rows (held in regs across both halves)
  uint4 pw[2][4];
  #pragma unroll
  for (int rt = 0; rt < 2; ++rt)
    #pragma unroll
    for (int reg = 0; reg < 4; ++reg)
      pw[rt][reg] = *(const uint4*)&pmL[(swr + rt * 16 + quad * 4 + reg) * 4];

  // ---------------- phase S: similarity + softmax partials ----------------
  float lacc[2][4], Sacc[2][4], Pcnt[2][4];
  #pragma unroll
  for (int rt = 0; rt < 2; ++rt)
    #pragma unroll
    for (int reg = 0; reg < 4; ++reg) { lacc[rt][reg] = 0; Sacc[rt][reg] = 0; Pcnt[rt][reg] = 0; }

  #pragma unroll
  for (int half = 0; half < 2; ++half) {
    const int gB = ((half ? N_ROWS : 0) + jbase) >> 4;
    f32x4 acc[2][8];
    #pragma unroll
    for (int rt = 0; rt < 2; ++rt)
      #pragma unroll
      for (int nt = 0; nt < 8; ++nt) acc[rt][nt] = (f32x4){0, 0, 0, 0};

    #pragma unroll
    for (int nt = 0; nt < 8; ++nt) {
      short8 bfr[4];
      #pragma unroll
      for (int kf = 0; kf < 4; ++kf)
        bfr[kf] = *(const short8*)(gz + (size_t)(((gB + nt) * 4 + kf) * 64 + lane) * 16);
      #pragma unroll
      for (int rt = 0; rt < 2; ++rt)
        #pragma unroll
        for (int kf = 0; kf < 4; ++kf)
          acc[rt][nt] = __builtin_amdgcn_mfma_f32_16x16x32_bf16(
              afr[rt][kf], bfr[kf], acc[rt][nt], 0, 0, 0);
    }

    if (!diag) {
      // slim: same mask both halves, no self/aug; P via popcount at the end
      #pragma unroll
      for (int rt = 0; rt < 2; ++rt)
        #pragma unroll
        for (int nt = 0; nt < 8; ++nt) {
          const int bitpos = (nt & 1) * 16 + col;
          #pragma unroll
          for (int reg = 0; reg < 4; ++reg) {
            const unsigned int w = ((const unsigned int*)&pw[rt][reg])[nt >> 1];
            const float d = acc[rt][nt][reg];
            lacc[rt][reg] += exp2f(fmaf(d, C_EXP, -C_EXP));
            if ((w >> bitpos) & 1) Sacc[rt][reg] += d;
          }
        }
    } else {
      const bool left = (half == 0);
      #pragma unroll
      for (int rt = 0; rt < 2; ++rt)
        #pragma unroll
        for (int nt = 0; nt < 8; ++nt) {
          const int joff = nt * 16 + col;
          const int jc = jbase + joff;
          const int bitpos = joff & 31;
          #pragma unroll
          for (int reg = 0; reg < 4; ++reg) {
            const int i = ibase + swr + rt * 16 + quad * 4 + reg;
            const unsigned int w = ((const unsigned int*)&pw[rt][reg])[nt >> 1];
            const float d = acc[rt][nt][reg];
            const bool bit = (w >> bitpos) & 1;
            const bool self = left && (jc == i);
            const bool pos = left ? (bit && !self) : (bit || (jc == i));
            const float e = exp2f(fmaf(d, C_EXP, -C_EXP));
            if (!self) lacc[rt][reg] += e;
            if (pos) { Sacc[rt][reg] += d; Pcnt[rt][reg] += 1.0f; }
          }
        }
    }
  }

  // ---- reduce across the 16 col-lanes, atomically accumulate per-anchor ----
  #pragma unroll
  for (int rt = 0; rt < 2; ++rt)
    #pragma unroll
    for (int reg = 0; reg < 4; ++reg) {
      float l = lacc[rt][reg], S = Sacc[rt][reg], P = Pcnt[rt][reg];
      #pragma unroll
      for (int m = 1; m < 16; m <<= 1) {
        l += __shfl_xor(l, m);
        S += __shfl_xor(S, m);
        if (diag) P += __shfl_xor(P, m);
      }
      if (col == 0) {
        const int i = ibase + swr + rt * 16 + quad * 4 + reg;
        if (!diag) {
          const uint4 w = pw[rt][reg];
          P = 2.0f * (float)(__popc(w.x) + __popc(w.y) + __popc(w.z) + __popc(w.w));
        }
        atomicAdd(&part[i], l);
        atomicAdd(&part[4096 + i], S);
        atomicAdd(&part[8192 + i], P);
      }
    }
}

// ---------------- kernel 3: per-anchor loss + atomic final reduce ----------------
__global__ __launch_bounds__(128) void k_loss(
    const float* __restrict__ part, float* __restrict__ out)
{
  const int a = blockIdx.x * 128 + threadIdx.x;   // 0..4095
  const float l = part[a];
  const float S = part[4096 + a];
  const float P = part[8192 + a];
  const float np = fmaxf(P, 1.0f);
  float v = INV_TAU + logf(l + 1e-8f) - (S * INV_TAU) / np;
  #pragma unroll
  for (int off = 32; off > 0; off >>= 1) v += __shfl_xor(v, off);
  __shared__ float ws2[2];
  const int wave = threadIdx.x >> 6, lane = threadIdx.x & 63;
  if (lane == 0) ws2[wave] = v;
  __syncthreads();
  if (threadIdx.x == 0) atomicAdd(out, (ws2[0] + ws2[1]) * (1.0f / (float)N_ROWS));
}

extern "C" void kernel_launch(void* const* d_in, const int* in_sizes, int n_in,
                              void* d_out, int out_size, void* d_ws, size_t ws_size,
                              hipStream_t stream) {
  const float* z1 = (const float*)d_in[0];
  const float* z2 = (const float*)d_in[1];
  const int* labels = (const int*)d_in[2];
  float* out = (float*)d_out;
  char* ws = (char*)d_ws;

  unsigned int* zbf    = (unsigned int*)(ws);
  uint2* labs8         = (uint2*)(ws + 2097152);
  int* s               = (int*)(ws + 4194304);
  float* part          = (float*)(ws + 4210688);

  hipLaunchKernelGGL(k_norm_pack, dim3(2048), dim3(256), 0, stream,
                     z1, z2, labels, zbf, labs8, s, part, out);
  hipLaunchKernelGGL(k_fused, dim3(32, 32), dim3(256), 0, stream,
                     (const unsigned char*)labs8, s, (const unsigned short*)zbf, part);
  hipLaunchKernelGGL(k_loss, dim3(32), dim3(128), 0, stream, part, out);
}

// Round 10
// 107.772 us; speedup vs baseline: 1.4077x; 1.0582x over previous
//
#include <hip/hip_runtime.h>
#include <math.h>

#define N_ROWS 4096
#define DIM    128
#define A_LAB  512
#define INV_TAU 14.285714285714286f
#define C_EXP   20.609929155556620f   // INV_TAU * log2(e)

typedef __attribute__((ext_vector_type(8))) short short8;   // 8 bf16 (4 VGPRs)
typedef __attribute__((ext_vector_type(4))) float f32x4;    // MFMA C/D frag (16x16)
typedef __attribute__((ext_vector_type(4))) int i32x4;      // i8 MFMA A/B frag
typedef __attribute__((ext_vector_type(16))) int i32x16;    // i8 MFMA C/D frag (32x32)

// ---------------- workspace layout (bytes) ----------------
// zbf   u16 [8192*128]   @ 0          (2,097,152)  FRAG-MAJOR (see k_norm_pack)
// labs8 i8  [4096*512]   @ 2,097,152  (2,097,152)  FRAG-MAJOR (see k_norm_pack)
// s     i32 [4096]       @ 4,194,304  (16,384)
// part  f32 [3*4096]     @ 4,210,688  (49,152)     atomically accumulated
//
// zbf frag-major: block (g,kf), g=row>>4 (0..511), kf=0..3; block = 64 lanes x 16B
//   lane l holds row g*16+(l&15), 16B-unit kf*4+(l>>4) -> one coalesced dwordx4
//   per bf16 16x16x32 A/B fragment.   [verified absmax 0.0, R9]
// labs frag-major: block (g,ks), g=row>>5 (0..127), ks=0..15; block = 64 x 16B
//   lane l holds row g*32+(l&31), k-bytes ks*32+(l>>5)*16 -> one coalesced
//   dwordx4 per i8 32x32x32 A/B fragment.   [verified absmax 0.0, R9]

__device__ __forceinline__ unsigned short f2bf(float f) {
  unsigned int u = __builtin_bit_cast(unsigned int, f);
  u += 0x7fffu + ((u >> 16) & 1u);            // round-to-nearest-even
  return (unsigned short)(u >> 16);
}

// ------------ kernel 1: L2-normalize (-> bf16, frag-major) + labels -> i8 frag-major ------------
__global__ __launch_bounds__(256) void k_norm_pack(
    const float* __restrict__ z1, const float* __restrict__ z2,
    const int* __restrict__ labels,
    unsigned int* __restrict__ zbf, uint2* __restrict__ labs8,
    int* __restrict__ s, float* __restrict__ part, float* __restrict__ out)
{
  {
    const int idx = blockIdx.x * 256 + threadIdx.x;
    if (idx < 3 * 4096) part[idx] = 0.0f;
    if (idx == 0) out[0] = 0.0f;
  }
  const int wave = threadIdx.x >> 6, lane = threadIdx.x & 63;
  const int r = blockIdx.x * 4 + wave;         // 0..8191
  const float* src = (r < N_ROWS) ? (z1 + (size_t)r * DIM)
                                  : (z2 + (size_t)(r - N_ROWS) * DIM);
  float2 x = ((const float2*)src)[lane];
  float ss = x.x * x.x + x.y * x.y;
  #pragma unroll
  for (int off = 32; off > 0; off >>= 1) ss += __shfl_xor(ss, off);
  const float inv = 1.0f / fmaxf(sqrtf(ss), 1e-12f);
  const unsigned int lo = f2bf(x.x * inv);
  const unsigned int hi = f2bf(x.y * inv);
  {
    // row r, dword index 'lane' (bytes lane*4). unit u=lane>>2, dword p=lane&3.
    const int u = lane >> 2, p = lane & 3;
    const int kf = u >> 2, quad = u & 3;
    const int g = r >> 4;
    zbf[(size_t)(((g * 4 + kf) * 64) + ((r & 15) + (quad << 4))) * 4 + p] = (hi << 16) | lo;
  }

  if (r < N_ROWS) {
    const int4* lp = (const int4*)(labels + (size_t)r * A_LAB);
    const int4 a = lp[2 * lane], b = lp[2 * lane + 1];
    const unsigned int w0 = (unsigned int)(a.x != 0)       | ((unsigned int)(a.y != 0) << 8)
                          | ((unsigned int)(a.z != 0) << 16) | ((unsigned int)(a.w != 0) << 24);
    const unsigned int w1 = (unsigned int)(b.x != 0)       | ((unsigned int)(b.y != 0) << 8)
                          | ((unsigned int)(b.z != 0) << 16) | ((unsigned int)(b.w != 0) << 24);
    uint2 v; v.x = w0; v.y = w1;
    // row r, bytes lane*8..+8: unit ul=lane>>1, half hp=lane&1; ks=ul>>1, h=ul&1
    const int ul = lane >> 1, hp = lane & 1;
    const int ks = ul >> 1, h = ul & 1;
    const int g = r >> 5;
    labs8[(size_t)(((g * 16 + ks) * 64) + ((r & 31) + (h << 5))) * 2 + hp] = v;
    int cnt = __popc(w0) + __popc(w1);         // bytes are 0/1 -> popc == byte sum
    #pragma unroll
    for (int off = 32; off > 0; off >>= 1) cnt += __shfl_xor(cnt, off);
    if (lane == 0) s[r] = cnt;
  }
}

// ------------ kernel 2: FUSED jaccard + sim + masked-softmax, 512 threads ------------
// Block (bi,bj): anchors [128bi..+128) x cols {[128bj..+128), [4096+128bj..+128)}.
// 8 waves/block to halve each wave's serial dependency chain and triple
// resident waves/CU vs the 256-thread variant (R9 starved: occ 18%).
// Phase J: wave (wr,wc) in 2x4 grid, tile 64 rows x 32 cols; 2 MFMA/k-step.
// Phase S: each wave 16 anchor rows x 128 cols x both halves.
// Frag-major global-direct loads (1 coalesced KB/frag); only LDS = 2 KB pmL;
// exactly ONE __syncthreads.
__global__ __launch_bounds__(512, 4) void k_fused(
    const unsigned char* __restrict__ labs8, const int* __restrict__ s,
    const unsigned short* __restrict__ zbf, float* __restrict__ part)
{
  __shared__ unsigned int pmL[128 * 4];       // pos-bits: [local row][col word]
  const int tid = threadIdx.x;
  const int ibase = blockIdx.x * 128, jbase = blockIdx.y * 128;
  const int wave = tid >> 6, lane = tid & 63;
  const bool diag = (ibase == jbase);
  const char* gl = (const char*)labs8;
  const char* gz = (const char*)zbf;

  // ---------------- phase J: jaccard (frag-major direct loads) ----------------
  const int jwr = (wave >> 2) * 64;           // rows: waves 0-3 -> 0, 4-7 -> 64
  const int jwc = (wave & 3) * 32;            // cols: 32-wide slice per wave
  const int col32 = lane & 31, h = lane >> 5;

  const int s3i = 3 * s[ibase + jwr + lane];        // this wave's 64 rows
  const int s3j = 3 * s[jbase + jwc + col32];       // this lane's col

  i32x16 jacc[2];
  #pragma unroll
  for (int rt = 0; rt < 2; ++rt)
    #pragma unroll
    for (int e = 0; e < 16; ++e) jacc[rt][e] = 0;

  const int gI = (ibase + jwr) >> 5;          // two 32-row groups: gI, gI+1
  const int gJ = (jbase + jwc) >> 5;          // one 32-row group
  #pragma unroll
  for (int ks = 0; ks < 16; ++ks) {
    i32x4 a[2], b;
    #pragma unroll
    for (int rt = 0; rt < 2; ++rt)
      a[rt] = *(const i32x4*)(gl + (size_t)(((gI + rt) * 16 + ks) * 64 + lane) * 16);
    b = *(const i32x4*)(gl + (size_t)((gJ * 16 + ks) * 64 + lane) * 16);
    #pragma unroll
    for (int rt = 0; rt < 2; ++rt)
      jacc[rt] = __builtin_amdgcn_mfma_i32_32x32x32_i8(a[rt], b, jacc[rt], 0, 0, 0);
  }

  // jac epilogue: threshold + ballot -> pmL (each wave owns 64 rows x 1 word)
  const int wl = wave & 3;
  #pragma unroll
  for (int rt = 0; rt < 2; ++rt)
    #pragma unroll
    for (int reg = 0; reg < 16; ++reg) {
      const int r0 = (reg & 3) + 8 * (reg >> 2);
      const int si = __shfl(s3i, rt * 32 + r0 + 4 * h);
      const bool pred = 13 * jacc[rt][reg] >= si + s3j;
      const unsigned long long bal = __ballot(pred);
      const int lr = jwr + rt * 32 + r0;
      if (lane == 0)      pmL[lr * 4 + wl]       = (unsigned int)bal;
      else if (lane == 1) pmL[(lr + 4) * 4 + wl] = (unsigned int)(bal >> 32);
    }

  // sim A-fragments (issued before the barrier; independent of pmL)
  const int col = lane & 15, quad = lane >> 4;
  const int srow = wave * 16;                    // this wave: 16 anchor rows
  const int gA = (ibase + srow) >> 4;
  short8 afr[4];
  #pragma unroll
  for (int kf = 0; kf < 4; ++kf)
    afr[kf] = *(const short8*)(gz + (size_t)((gA * 4 + kf) * 64 + lane) * 16);

  __syncthreads();   // the ONLY barrier: pmL visible to all waves

  // mask words for this wave's rows (held in regs across both halves)
  uint4 pw[4];
  #pragma unroll
  for (int reg = 0; reg < 4; ++reg)
    pw[reg] = *(const uint4*)&pmL[(srow + quad * 4 + reg) * 4];

  // ---------------- phase S: similarity + softmax partials ----------------
  float lacc[4], Sacc[4], Pcnt[4];
  #pragma unroll
  for (int reg = 0; reg < 4; ++reg) { lacc[reg] = 0; Sacc[reg] = 0; Pcnt[reg] = 0; }

  #pragma unroll
  for (int half = 0; half < 2; ++half) {
    const int gB = ((half ? N_ROWS : 0) + jbase) >> 4;
    f32x4 acc[8];
    #pragma unroll
    for (int nt = 0; nt < 8; ++nt) acc[nt] = (f32x4){0, 0, 0, 0};

    #pragma unroll
    for (int nt = 0; nt < 8; ++nt) {
      short8 bfr[4];
      #pragma unroll
      for (int kf = 0; kf < 4; ++kf)
        bfr[kf] = *(const short8*)(gz + (size_t)(((gB + nt) * 4 + kf) * 64 + lane) * 16);
      #pragma unroll
      for (int kf = 0; kf < 4; ++kf)
        acc[nt] = __builtin_amdgcn_mfma_f32_16x16x32_bf16(afr[kf], bfr[kf], acc[nt], 0, 0, 0);
    }

    if (!diag) {
      // slim: same mask both halves, no self/aug; P via popcount at the end
      #pragma unroll
      for (int nt = 0; nt < 8; ++nt) {
        const int bitpos = (nt & 1) * 16 + col;
        #pragma unroll
        for (int reg = 0; reg < 4; ++reg) {
          const unsigned int w = ((const unsigned int*)&pw[reg])[nt >> 1];
          const float d = acc[nt][reg];
          lacc[reg] += exp2f(fmaf(d, C_EXP, -C_EXP));
          if ((w >> bitpos) & 1) Sacc[reg] += d;
        }
      }
    } else {
      const bool left = (half == 0);
      #pragma unroll
      for (int nt = 0; nt < 8; ++nt) {
        const int joff = nt * 16 + col;
        const int jc = jbase + joff;
        const int bitpos = joff & 31;
        #pragma unroll
        for (int reg = 0; reg < 4; ++reg) {
          const int i = ibase + srow + quad * 4 + reg;
          const unsigned int w = ((const unsigned int*)&pw[reg])[nt >> 1];
          const float d = acc[nt][reg];
          const bool bit = (w >> bitpos) & 1;
          const bool self = left && (jc == i);
          const bool pos = left ? (bit && !self) : (bit || (jc == i));
          const float e = exp2f(fmaf(d, C_EXP, -C_EXP));
          if (!self) lacc[reg] += e;
          if (pos) { Sacc[reg] += d; Pcnt[reg] += 1.0f; }
        }
      }
    }
  }

  // ---- reduce across the 16 col-lanes, atomically accumulate per-anchor ----
  #pragma unroll
  for (int reg = 0; reg < 4; ++reg) {
    float l = lacc[reg], S = Sacc[reg], P = Pcnt[reg];
    #pragma unroll
    for (int m = 1; m < 16; m <<= 1) {
      l += __shfl_xor(l, m);
      S += __shfl_xor(S, m);
      if (diag) P += __shfl_xor(P, m);
    }
    if (col == 0) {
      const int li = srow + quad * 4 + reg;
      const int i = ibase + li;
      if (!diag) {
        const uint4 w = pw[reg];
        P = 2.0f * (float)(__popc(w.x) + __popc(w.y) + __popc(w.z) + __popc(w.w));
      }
      atomicAdd(&part[i], l);
      atomicAdd(&part[4096 + i], S);
      atomicAdd(&part[8192 + i], P);
    }
  }
}

// ---------------- kernel 3: per-anchor loss + atomic final reduce ----------------
__global__ __launch_bounds__(128) void k_loss(
    const float* __restrict__ part, float* __restrict__ out)
{
  const int a = blockIdx.x * 128 + threadIdx.x;   // 0..4095
  const float l = part[a];
  const float S = part[4096 + a];
  const float P = part[8192 + a];
  const float np = fmaxf(P, 1.0f);
  float v = INV_TAU + logf(l + 1e-8f) - (S * INV_TAU) / np;
  #pragma unroll
  for (int off = 32; off > 0; off >>= 1) v += __shfl_xor(v, off);
  __shared__ float ws2[2];
  const int wave = threadIdx.x >> 6, lane = threadIdx.x & 63;
  if (lane == 0) ws2[wave] = v;
  __syncthreads();
  if (threadIdx.x == 0) atomicAdd(out, (ws2[0] + ws2[1]) * (1.0f / (float)N_ROWS));
}

extern "C" void kernel_launch(void* const* d_in, const int* in_sizes, int n_in,
                              void* d_out, int out_size, void* d_ws, size_t ws_size,
                              hipStream_t stream) {
  const float* z1 = (const float*)d_in[0];
  const float* z2 = (const float*)d_in[1];
  const int* labels = (const int*)d_in[2];
  float* out = (float*)d_out;
  char* ws = (char*)d_ws;

  unsigned int* zbf    = (unsigned int*)(ws);
  uint2* labs8         = (uint2*)(ws + 2097152);
  int* s               = (int*)(ws + 4194304);
  float* part          = (float*)(ws + 4210688);

  hipLaunchKernelGGL(k_norm_pack, dim3(2048), dim3(256), 0, stream,
                     z1, z2, labels, zbf, labs8, s, part, out);
  hipLaunchKernelGGL(k_fused, dim3(32, 32), dim3(512), 0, stream,
                     (const unsigned char*)labs8, s, (const unsigned short*)zbf, part);
  hipLaunchKernelGGL(k_loss, dim3(32), dim3(128), 0, stream, part, out);
}